// Round 2
// baseline (105.540 us; speedup 1.0000x reference)
//
#include <hip/hip_runtime.h>
#include <math.h>

#define BLOCK 256
#define NWAVE (BLOCK / 64)
#define NB 2048

__device__ __forceinline__ float finlen(float b, float d) {
    float l = b - d;
    return isfinite(l) ? l : 0.0f;
}

__device__ __forceinline__ void acc_sq(const float4 v, float& s) {
    const float la = finlen(v.x, v.y);
    const float lb = finlen(v.z, v.w);
    s += la * la + lb * lb;
}

__device__ __forceinline__ void acc_sq_max(const float4 v, float& s, float& m) {
    const float la = finlen(v.x, v.y);
    const float lb = finlen(v.z, v.w);
    s += la * la + lb * lb;
    m = fmaxf(m, fmaxf(la, lb));
}

// Block-level reduction of (s0,s1,s2 sums; m0 max). Result valid in thread 0.
__device__ __forceinline__ void block_reduce(float& s0, float& s1, float& s2, float& m0) {
    __shared__ float ls0[NWAVE], ls1[NWAVE], ls2[NWAVE], lm0[NWAVE];
    const int lane = threadIdx.x & 63;
    const int wid  = threadIdx.x >> 6;
    #pragma unroll
    for (int off = 32; off > 0; off >>= 1) {
        s0 += __shfl_down(s0, off);
        s1 += __shfl_down(s1, off);
        s2 += __shfl_down(s2, off);
        m0 = fmaxf(m0, __shfl_down(m0, off));
    }
    if (lane == 0) { ls0[wid] = s0; ls1[wid] = s1; ls2[wid] = s2; lm0[wid] = m0; }
    __syncthreads();
    if (threadIdx.x == 0) {
        #pragma unroll
        for (int w = 1; w < NWAVE; ++w) {
            s0 += ls0[w];
            s1 += ls1[w];
            s2 += ls2[w];
            m0 = fmaxf(m0, lm0[w]);
        }
    }
}

__device__ __forceinline__ void write_final(float* out, float s0, float s1, float s2, float m0) {
    const float top2 = m0 * m0;
    const float t01 = 1.0f - top2;
    const float t0  = s0 - top2;
    out[0] = t01 + t0 + s1 + s2;  // loss
    out[1] = t01;
    out[2] = t0;
    out[3] = s1;
    out[4] = s2;
}

// Single fused kernel: grid-stride reduce with 6 independent float4 loads per
// iteration (MLP), then last-arriving block (device-fence + atomic counter)
// reduces the per-block partials and writes the 5 outputs.
__global__ __launch_bounds__(BLOCK) void toploss_fused(
    const float* __restrict__ g0, const float* __restrict__ g1,
    const float* __restrict__ g2, int npairs,
    float4* __restrict__ part, unsigned int* __restrict__ counter,
    float* __restrict__ out)
{
    const float4* a0 = (const float4*)g0;
    const float4* a1 = (const float4*)g1;
    const float4* a2 = (const float4*)g2;
    const long n4 = (long)(npairs >> 1);
    const int  nb = (int)gridDim.x;
    const long stride = (long)nb * BLOCK;
    const long tid = (long)blockIdx.x * BLOCK + threadIdx.x;

    float s0 = 0.0f, s1 = 0.0f, s2 = 0.0f, m0 = -INFINITY;

    long i = tid;
    // 2x-stride unrolled main loop: 6 independent coalesced float4 loads
    // (96 B/lane) issued back-to-back before any consume.
    for (; i + stride < n4; i += 2 * stride) {
        const float4 v0a = a0[i];
        const float4 v1a = a1[i];
        const float4 v2a = a2[i];
        const float4 v0b = a0[i + stride];
        const float4 v1b = a1[i + stride];
        const float4 v2b = a2[i + stride];
        acc_sq_max(v0a, s0, m0);
        acc_sq_max(v0b, s0, m0);
        acc_sq(v1a, s1);
        acc_sq(v1b, s1);
        acc_sq(v2a, s2);
        acc_sq(v2b, s2);
    }
    for (; i < n4; i += stride) {
        acc_sq_max(a0[i], s0, m0);
        acc_sq(a1[i], s1);
        acc_sq(a2[i], s2);
    }
    // odd-pair scalar tail (not hit for 8M bars, kept for generality)
    if (tid == 0 && (npairs & 1)) {
        const int j = npairs - 1;
        const float l0 = finlen(g0[2 * j], g0[2 * j + 1]);
        const float l1 = finlen(g1[2 * j], g1[2 * j + 1]);
        const float l2 = finlen(g2[2 * j], g2[2 * j + 1]);
        s0 += l0 * l0; s1 += l1 * l1; s2 += l2 * l2;
        m0 = fmaxf(m0, l0);
    }

    block_reduce(s0, s1, s2, m0);

    __shared__ int is_last;
    if (threadIdx.x == 0) {
        part[blockIdx.x] = make_float4(s0, s1, s2, m0);
        __threadfence();                       // release partials (device scope)
        const unsigned old = atomicAdd(counter, 1u);
        is_last = (old == (unsigned)(nb - 1)) ? 1 : 0;
    }
    __syncthreads();
    if (is_last) {
        __threadfence();                       // acquire other blocks' partials
        float t0 = 0.0f, t1 = 0.0f, t2 = 0.0f, tm = -INFINITY;
        for (int j = threadIdx.x; j < nb; j += BLOCK) {
            const float4 p = part[j];
            t0 += p.x; t1 += p.y; t2 += p.z;
            tm = fmaxf(tm, p.w);
        }
        block_reduce(t0, t1, t2, tm);
        if (threadIdx.x == 0) write_final(out, t0, t1, t2, tm);
    }
}

extern "C" void kernel_launch(void* const* d_in, const int* in_sizes, int n_in,
                              void* d_out, int out_size, void* d_ws, size_t ws_size,
                              hipStream_t stream) {
    const float* g0 = (const float*)d_in[0];
    const float* g1 = (const float*)d_in[1];
    const float* g2 = (const float*)d_in[2];
    float* out = (float*)d_out;

    // ws layout: [0..3] counter | [256 ...] per-block float4 partials
    unsigned int* counter = (unsigned int*)d_ws;
    float4* part = (float4*)((char*)d_ws + 256);

    const int npairs = in_sizes[0] / 2;  // bars per diagram

    int nb = NB;  // 256 CUs x 8 blocks
    const size_t cap = (ws_size > 256) ? (ws_size - 256) / sizeof(float4) : 0;
    if ((size_t)nb > cap) nb = (int)cap;
    if (nb < 1) nb = 1;

    hipMemsetAsync(counter, 0, sizeof(unsigned int), stream);
    toploss_fused<<<nb, BLOCK, 0, stream>>>(g0, g1, g2, npairs, part, counter, out);
}

// Round 3
// 102.005 us; speedup vs baseline: 1.0347x; 1.0347x over previous
//
#include <hip/hip_runtime.h>
#include <math.h>

#define BLOCK 256
#define NWAVE (BLOCK / 64)
#define NB 2048

__device__ __forceinline__ float finlen(float b, float d) {
    float l = b - d;
    return isfinite(l) ? l : 0.0f;
}

__device__ __forceinline__ void acc_sq(const float4 v, float& s) {
    const float la = finlen(v.x, v.y);
    const float lb = finlen(v.z, v.w);
    s += la * la + lb * lb;
}

__device__ __forceinline__ void acc_sq_max(const float4 v, float& s, float& m) {
    const float la = finlen(v.x, v.y);
    const float lb = finlen(v.z, v.w);
    s += la * la + lb * lb;
    m = fmaxf(m, fmaxf(la, lb));
}

// Block-level reduction of (s0,s1,s2 sums; m0 max). Result valid in thread 0.
__device__ __forceinline__ void block_reduce(float& s0, float& s1, float& s2, float& m0) {
    __shared__ float ls0[NWAVE], ls1[NWAVE], ls2[NWAVE], lm0[NWAVE];
    const int lane = threadIdx.x & 63;
    const int wid  = threadIdx.x >> 6;
    #pragma unroll
    for (int off = 32; off > 0; off >>= 1) {
        s0 += __shfl_down(s0, off);
        s1 += __shfl_down(s1, off);
        s2 += __shfl_down(s2, off);
        m0 = fmaxf(m0, __shfl_down(m0, off));
    }
    if (lane == 0) { ls0[wid] = s0; ls1[wid] = s1; ls2[wid] = s2; lm0[wid] = m0; }
    __syncthreads();
    if (threadIdx.x == 0) {
        #pragma unroll
        for (int w = 1; w < NWAVE; ++w) {
            s0 += ls0[w];
            s1 += ls1[w];
            s2 += ls2[w];
            m0 = fmaxf(m0, lm0[w]);
        }
    }
}

__device__ __forceinline__ void write_final(float* out, float s0, float s1, float s2, float m0) {
    const float top2 = m0 * m0;
    const float t01 = 1.0f - top2;
    const float t0  = s0 - top2;
    out[0] = t01 + t0 + s1 + s2;  // loss
    out[1] = t01;
    out[2] = t0;
    out[3] = s1;
    out[4] = s2;
}

// Round-1-proven loop structure (three sequential per-array grid-stride loops,
// 2-way unrolled), fused finish via agent-scope atomics (NO __threadfence:
// device fences imply L2 writeback/invalidate on non-coherent per-XCD L2s,
// which collapsed BW in R2). Agent-scope atomic stores/loads use sc-bit
// coherent accesses that bypass L2 for just these few bytes.
__global__ __launch_bounds__(BLOCK) void toploss_fused(
    const float* __restrict__ g0, const float* __restrict__ g1,
    const float* __restrict__ g2, int npairs,
    float* __restrict__ part, unsigned int* __restrict__ counter,
    float* __restrict__ out)
{
    const float4* a0 = (const float4*)g0;
    const float4* a1 = (const float4*)g1;
    const float4* a2 = (const float4*)g2;
    const long n4 = (long)(npairs >> 1);
    const int  nb = (int)gridDim.x;
    const long stride = (long)nb * BLOCK;
    const long tid = (long)blockIdx.x * BLOCK + threadIdx.x;

    float s0 = 0.0f, s1 = 0.0f, s2 = 0.0f, m0 = -INFINITY;

    long i = tid;
    for (; i + stride < n4; i += 2 * stride) {
        const float4 va = a0[i];
        const float4 vb = a0[i + stride];
        acc_sq_max(va, s0, m0);
        acc_sq_max(vb, s0, m0);
    }
    for (; i < n4; i += stride) acc_sq_max(a0[i], s0, m0);

    i = tid;
    for (; i + stride < n4; i += 2 * stride) {
        const float4 va = a1[i];
        const float4 vb = a1[i + stride];
        acc_sq(va, s1);
        acc_sq(vb, s1);
    }
    for (; i < n4; i += stride) acc_sq(a1[i], s1);

    i = tid;
    for (; i + stride < n4; i += 2 * stride) {
        const float4 va = a2[i];
        const float4 vb = a2[i + stride];
        acc_sq(va, s2);
        acc_sq(vb, s2);
    }
    for (; i < n4; i += stride) acc_sq(a2[i], s2);

    // odd-pair scalar tail (not hit for 8M bars, kept for generality)
    if (tid == 0 && (npairs & 1)) {
        const int j = npairs - 1;
        const float l0 = finlen(g0[2 * j], g0[2 * j + 1]);
        const float l1 = finlen(g1[2 * j], g1[2 * j + 1]);
        const float l2 = finlen(g2[2 * j], g2[2 * j + 1]);
        s0 += l0 * l0; s1 += l1 * l1; s2 += l2 * l2;
        m0 = fmaxf(m0, l0);
    }

    block_reduce(s0, s1, s2, m0);

    __shared__ int is_last;
    if (threadIdx.x == 0) {
        float* p = part + (size_t)blockIdx.x * 4;
        __hip_atomic_store(p + 0, s0, __ATOMIC_RELAXED, __HIP_MEMORY_SCOPE_AGENT);
        __hip_atomic_store(p + 1, s1, __ATOMIC_RELAXED, __HIP_MEMORY_SCOPE_AGENT);
        __hip_atomic_store(p + 2, s2, __ATOMIC_RELAXED, __HIP_MEMORY_SCOPE_AGENT);
        __hip_atomic_store(p + 3, m0, __ATOMIC_RELAXED, __HIP_MEMORY_SCOPE_AGENT);
        const unsigned old = __hip_atomic_fetch_add(counter, 1u, __ATOMIC_ACQ_REL,
                                                    __HIP_MEMORY_SCOPE_AGENT);
        is_last = (old == (unsigned)(nb - 1)) ? 1 : 0;
    }
    __syncthreads();
    if (is_last) {
        float t0 = 0.0f, t1 = 0.0f, t2 = 0.0f, tm = -INFINITY;
        for (int j = threadIdx.x; j < nb; j += BLOCK) {
            const float* p = part + (size_t)j * 4;
            t0 += __hip_atomic_load(p + 0, __ATOMIC_RELAXED, __HIP_MEMORY_SCOPE_AGENT);
            t1 += __hip_atomic_load(p + 1, __ATOMIC_RELAXED, __HIP_MEMORY_SCOPE_AGENT);
            t2 += __hip_atomic_load(p + 2, __ATOMIC_RELAXED, __HIP_MEMORY_SCOPE_AGENT);
            tm = fmaxf(tm, __hip_atomic_load(p + 3, __ATOMIC_RELAXED, __HIP_MEMORY_SCOPE_AGENT));
        }
        block_reduce(t0, t1, t2, tm);
        if (threadIdx.x == 0) write_final(out, t0, t1, t2, tm);
    }
}

extern "C" void kernel_launch(void* const* d_in, const int* in_sizes, int n_in,
                              void* d_out, int out_size, void* d_ws, size_t ws_size,
                              hipStream_t stream) {
    const float* g0 = (const float*)d_in[0];
    const float* g1 = (const float*)d_in[1];
    const float* g2 = (const float*)d_in[2];
    float* out = (float*)d_out;

    // ws layout: [0..3] counter | [256 ...] per-block 4-float partials
    unsigned int* counter = (unsigned int*)d_ws;
    float* part = (float*)((char*)d_ws + 256);

    const int npairs = in_sizes[0] / 2;  // bars per diagram

    int nb = NB;  // 256 CUs x 8 blocks, fully co-resident
    const size_t cap = (ws_size > 256) ? (ws_size - 256) / (4 * sizeof(float)) : 0;
    if ((size_t)nb > cap) nb = (int)cap;
    if (nb < 1) nb = 1;

    hipMemsetAsync(counter, 0, sizeof(unsigned int), stream);
    toploss_fused<<<nb, BLOCK, 0, stream>>>(g0, g1, g2, npairs, part, counter, out);
}

// Round 4
// 60.772 us; speedup vs baseline: 1.7367x; 1.6785x over previous
//
#include <hip/hip_runtime.h>
#include <math.h>

#define BLOCK 256
#define NWAVE (BLOCK / 64)
#define NB 2048

__device__ __forceinline__ float finlen(float b, float d) {
    float l = b - d;
    return isfinite(l) ? l : 0.0f;
}

__device__ __forceinline__ void acc_sq(const float4 v, float& s) {
    const float la = finlen(v.x, v.y);
    const float lb = finlen(v.z, v.w);
    s += la * la + lb * lb;
}

__device__ __forceinline__ void acc_sq_max(const float4 v, float& s, float& m) {
    const float la = finlen(v.x, v.y);
    const float lb = finlen(v.z, v.w);
    s += la * la + lb * lb;
    m = fmaxf(m, fmaxf(la, lb));
}

// Block-level reduction of (s0,s1,s2 sums; m0 max). Result valid in thread 0.
__device__ __forceinline__ void block_reduce(float& s0, float& s1, float& s2, float& m0) {
    __shared__ float ls0[NWAVE], ls1[NWAVE], ls2[NWAVE], lm0[NWAVE];
    const int lane = threadIdx.x & 63;
    const int wid  = threadIdx.x >> 6;
    #pragma unroll
    for (int off = 32; off > 0; off >>= 1) {
        s0 += __shfl_down(s0, off);
        s1 += __shfl_down(s1, off);
        s2 += __shfl_down(s2, off);
        m0 = fmaxf(m0, __shfl_down(m0, off));
    }
    if (lane == 0) { ls0[wid] = s0; ls1[wid] = s1; ls2[wid] = s2; lm0[wid] = m0; }
    __syncthreads();
    if (threadIdx.x == 0) {
        #pragma unroll
        for (int w = 1; w < NWAVE; ++w) {
            s0 += ls0[w];
            s1 += ls1[w];
            s2 += ls2[w];
            m0 = fmaxf(m0, lm0[w]);
        }
    }
}

__device__ __forceinline__ void write_final(float* out, float s0, float s1, float s2, float m0) {
    const float top2 = m0 * m0;
    const float t01 = 1.0f - top2;
    const float t0  = s0 - top2;
    out[0] = t01 + t0 + s1 + s2;  // loss
    out[1] = t01;
    out[2] = t0;
    out[3] = s1;
    out[4] = s2;
}

// R1's exact proven main-loop body (three simple sequential grid-stride loops),
// fused finish with ZERO fence semantics:
//  - partials: RELAXED agent-scope atomic stores (L2-bypassing, land at the
//    coherence point; no wbl2/inv cache maintenance, unlike release/acq-rel)
//  - ordering: explicit s_waitcnt vmcnt(0) = completion wait (NOT a cache
//    fence) before the RELAXED agent-scope counter RMW
//  - last block: relaxed agent-scope loads, data-dependent on the counter
//    value it observed, so they cannot start early and cannot hit stale cache.
__global__ __launch_bounds__(BLOCK) void toploss_fused(
    const float* __restrict__ g0, const float* __restrict__ g1,
    const float* __restrict__ g2, int npairs,
    float* __restrict__ part, unsigned int* __restrict__ counter,
    float* __restrict__ out)
{
    const float4* a0 = (const float4*)g0;
    const float4* a1 = (const float4*)g1;
    const float4* a2 = (const float4*)g2;
    const long n4 = (long)(npairs >> 1);
    const int  nb = (int)gridDim.x;
    const long stride = (long)nb * BLOCK;
    const long tid = (long)blockIdx.x * BLOCK + threadIdx.x;

    float s0 = 0.0f, s1 = 0.0f, s2 = 0.0f, m0 = -INFINITY;

    for (long i = tid; i < n4; i += stride) acc_sq_max(a0[i], s0, m0);
    for (long i = tid; i < n4; i += stride) acc_sq(a1[i], s1);
    for (long i = tid; i < n4; i += stride) acc_sq(a2[i], s2);

    // odd-pair scalar tail (not hit for 8M bars, kept for generality)
    if (tid == 0 && (npairs & 1)) {
        const int j = npairs - 1;
        const float l0 = finlen(g0[2 * j], g0[2 * j + 1]);
        const float l1 = finlen(g1[2 * j], g1[2 * j + 1]);
        const float l2 = finlen(g2[2 * j], g2[2 * j + 1]);
        s0 += l0 * l0; s1 += l1 * l1; s2 += l2 * l2;
        m0 = fmaxf(m0, l0);
    }

    block_reduce(s0, s1, s2, m0);

    __shared__ int is_last;
    if (threadIdx.x == 0) {
        float* p = part + (size_t)blockIdx.x * 4;
        __hip_atomic_store(p + 0, s0, __ATOMIC_RELAXED, __HIP_MEMORY_SCOPE_AGENT);
        __hip_atomic_store(p + 1, s1, __ATOMIC_RELAXED, __HIP_MEMORY_SCOPE_AGENT);
        __hip_atomic_store(p + 2, s2, __ATOMIC_RELAXED, __HIP_MEMORY_SCOPE_AGENT);
        __hip_atomic_store(p + 3, m0, __ATOMIC_RELAXED, __HIP_MEMORY_SCOPE_AGENT);
        // Completion wait for the 4 stores above (they bypass L2), NOT a
        // cache fence — no L2 writeback/invalidate is issued.
        asm volatile("s_waitcnt vmcnt(0)" ::: "memory");
        const unsigned old = __hip_atomic_fetch_add(counter, 1u, __ATOMIC_RELAXED,
                                                    __HIP_MEMORY_SCOPE_AGENT);
        is_last = (old == (unsigned)(nb - 1)) ? 1 : 0;
    }
    __syncthreads();
    if (is_last) {
        float t0 = 0.0f, t1 = 0.0f, t2 = 0.0f, tm = -INFINITY;
        for (int j = threadIdx.x; j < nb; j += BLOCK) {
            const float* p = part + (size_t)j * 4;
            t0 += __hip_atomic_load(p + 0, __ATOMIC_RELAXED, __HIP_MEMORY_SCOPE_AGENT);
            t1 += __hip_atomic_load(p + 1, __ATOMIC_RELAXED, __HIP_MEMORY_SCOPE_AGENT);
            t2 += __hip_atomic_load(p + 2, __ATOMIC_RELAXED, __HIP_MEMORY_SCOPE_AGENT);
            tm = fmaxf(tm, __hip_atomic_load(p + 3, __ATOMIC_RELAXED, __HIP_MEMORY_SCOPE_AGENT));
        }
        block_reduce(t0, t1, t2, tm);
        if (threadIdx.x == 0) write_final(out, t0, t1, t2, tm);
    }
}

extern "C" void kernel_launch(void* const* d_in, const int* in_sizes, int n_in,
                              void* d_out, int out_size, void* d_ws, size_t ws_size,
                              hipStream_t stream) {
    const float* g0 = (const float*)d_in[0];
    const float* g1 = (const float*)d_in[1];
    const float* g2 = (const float*)d_in[2];
    float* out = (float*)d_out;

    // ws layout: [0..3] counter | [256 ...] per-block 4-float partials
    unsigned int* counter = (unsigned int*)d_ws;
    float* part = (float*)((char*)d_ws + 256);

    const int npairs = in_sizes[0] / 2;  // bars per diagram

    int nb = NB;  // 256 CUs x 8 blocks, fully co-resident
    const size_t cap = (ws_size > 256) ? (ws_size - 256) / (4 * sizeof(float)) : 0;
    if ((size_t)nb > cap) nb = (int)cap;
    if (nb < 1) nb = 1;

    hipMemsetAsync(counter, 0, sizeof(unsigned int), stream);
    toploss_fused<<<nb, BLOCK, 0, stream>>>(g0, g1, g2, npairs, part, counter, out);
}

// Round 5
// 41.038 us; speedup vs baseline: 2.5718x; 1.4809x over previous
//
#include <hip/hip_runtime.h>
#include <math.h>

#define BLOCK 256
#define NWAVE (BLOCK / 64)
#define NB 2048

__device__ __forceinline__ float finlen(float b, float d) {
    float l = b - d;
    return isfinite(l) ? l : 0.0f;
}

__device__ __forceinline__ void acc_sq(const float4 v, float& s) {
    const float la = finlen(v.x, v.y);
    const float lb = finlen(v.z, v.w);
    s += la * la + lb * lb;
}

__device__ __forceinline__ void acc_sq_max(const float4 v, float& s, float& m) {
    const float la = finlen(v.x, v.y);
    const float lb = finlen(v.z, v.w);
    s += la * la + lb * lb;
    m = fmaxf(m, fmaxf(la, lb));
}

// Block-level reduction of (s0,s1,s2 sums; m0 max). Result valid in thread 0.
__device__ __forceinline__ void block_reduce(float& s0, float& s1, float& s2, float& m0) {
    __shared__ float ls0[NWAVE], ls1[NWAVE], ls2[NWAVE], lm0[NWAVE];
    const int lane = threadIdx.x & 63;
    const int wid  = threadIdx.x >> 6;
    #pragma unroll
    for (int off = 32; off > 0; off >>= 1) {
        s0 += __shfl_down(s0, off);
        s1 += __shfl_down(s1, off);
        s2 += __shfl_down(s2, off);
        m0 = fmaxf(m0, __shfl_down(m0, off));
    }
    if (lane == 0) { ls0[wid] = s0; ls1[wid] = s1; ls2[wid] = s2; lm0[wid] = m0; }
    __syncthreads();
    if (threadIdx.x == 0) {
        #pragma unroll
        for (int w = 1; w < NWAVE; ++w) {
            s0 += ls0[w];
            s1 += ls1[w];
            s2 += ls2[w];
            m0 = fmaxf(m0, lm0[w]);
        }
    }
}

__device__ __forceinline__ void write_final(float* out, float s0, float s1, float s2, float m0) {
    const float top2 = m0 * m0;
    const float t01 = 1.0f - top2;
    const float t0  = s0 - top2;
    out[0] = t01 + t0 + s1 + s2;  // loss
    out[1] = t01;
    out[2] = t0;
    out[3] = s1;
    out[4] = s2;
}

// Two-kernel structure (R1-proven: fused cross-block finish costs MORE than a
// second dispatch on gfx950 — uncached coherence-point loads + same-line RMW
// contention, R4 evidence). pass1: three sequential per-array grid-stride
// loops, each 4-way unrolled so 4 independent float4 loads are in flight per
// wave (R1's VGPR=12 build kept only ~1 → latency-bound at 5.5 TB/s).
__global__ __launch_bounds__(BLOCK) void pass1(
    const float* __restrict__ g0, const float* __restrict__ g1,
    const float* __restrict__ g2, float* __restrict__ part, int npairs)
{
    const float4* a0 = (const float4*)g0;
    const float4* a1 = (const float4*)g1;
    const float4* a2 = (const float4*)g2;
    const long n4 = (long)(npairs >> 1);
    const long tid = (long)blockIdx.x * BLOCK + threadIdx.x;
    const long stride = (long)gridDim.x * BLOCK;
    const long step4 = 4 * stride;

    float s0 = 0.0f, s1 = 0.0f, s2 = 0.0f, m0 = -INFINITY;

    long i = tid;
    for (; i + 3 * stride < n4; i += step4) {
        const float4 va = a0[i];
        const float4 vb = a0[i + stride];
        const float4 vc = a0[i + 2 * stride];
        const float4 vd = a0[i + 3 * stride];
        acc_sq_max(va, s0, m0);
        acc_sq_max(vb, s0, m0);
        acc_sq_max(vc, s0, m0);
        acc_sq_max(vd, s0, m0);
    }
    for (; i < n4; i += stride) acc_sq_max(a0[i], s0, m0);

    i = tid;
    for (; i + 3 * stride < n4; i += step4) {
        const float4 va = a1[i];
        const float4 vb = a1[i + stride];
        const float4 vc = a1[i + 2 * stride];
        const float4 vd = a1[i + 3 * stride];
        acc_sq(va, s1);
        acc_sq(vb, s1);
        acc_sq(vc, s1);
        acc_sq(vd, s1);
    }
    for (; i < n4; i += stride) acc_sq(a1[i], s1);

    i = tid;
    for (; i + 3 * stride < n4; i += step4) {
        const float4 va = a2[i];
        const float4 vb = a2[i + stride];
        const float4 vc = a2[i + 2 * stride];
        const float4 vd = a2[i + 3 * stride];
        acc_sq(va, s2);
        acc_sq(vb, s2);
        acc_sq(vc, s2);
        acc_sq(vd, s2);
    }
    for (; i < n4; i += stride) acc_sq(a2[i], s2);

    // odd-pair scalar tail (not hit for 8M bars, kept for generality)
    if (tid == 0 && (npairs & 1)) {
        const int j = npairs - 1;
        const float l0 = finlen(g0[2 * j], g0[2 * j + 1]);
        const float l1 = finlen(g1[2 * j], g1[2 * j + 1]);
        const float l2 = finlen(g2[2 * j], g2[2 * j + 1]);
        s0 += l0 * l0; s1 += l1 * l1; s2 += l2 * l2;
        m0 = fmaxf(m0, l0);
    }

    block_reduce(s0, s1, s2, m0);

    if (threadIdx.x == 0) {
        float* p = part + (size_t)blockIdx.x * 4;
        p[0] = s0; p[1] = s1; p[2] = s2; p[3] = m0;
    }
}

__global__ __launch_bounds__(BLOCK) void pass2(
    const float* __restrict__ part, int nblocks, float* __restrict__ out)
{
    float s0 = 0.0f, s1 = 0.0f, s2 = 0.0f, m0 = -INFINITY;
    for (int i = threadIdx.x; i < nblocks; i += BLOCK) {
        const float* p = part + (size_t)i * 4;
        s0 += p[0];
        s1 += p[1];
        s2 += p[2];
        m0 = fmaxf(m0, p[3]);
    }
    block_reduce(s0, s1, s2, m0);
    if (threadIdx.x == 0) write_final(out, s0, s1, s2, m0);
}

extern "C" void kernel_launch(void* const* d_in, const int* in_sizes, int n_in,
                              void* d_out, int out_size, void* d_ws, size_t ws_size,
                              hipStream_t stream) {
    const float* g0 = (const float*)d_in[0];
    const float* g1 = (const float*)d_in[1];
    const float* g2 = (const float*)d_in[2];
    float* out = (float*)d_out;
    float* part = (float*)d_ws;

    const int npairs = in_sizes[0] / 2;  // bars per diagram

    int nblocks = NB;  // 256 CUs x 8 blocks co-resident
    const size_t cap = ws_size / (4 * sizeof(float));
    if ((size_t)nblocks > cap) nblocks = (int)cap;

    if (nblocks >= 2) {
        pass1<<<nblocks, BLOCK, 0, stream>>>(g0, g1, g2, part, npairs);
        pass2<<<1, BLOCK, 0, stream>>>(part, nblocks, out);
    } else {
        // degenerate ws fallback: single block does everything via pass1+pass2
        pass1<<<1, BLOCK, 0, stream>>>(g0, g1, g2, part, npairs);
        pass2<<<1, BLOCK, 0, stream>>>(part, 1, out);
    }
}

// Round 6
// 39.011 us; speedup vs baseline: 2.7054x; 1.0520x over previous
//
#include <hip/hip_runtime.h>
#include <math.h>

#define BLOCK 256
#define NWAVE (BLOCK / 64)
#define NB 2048

__device__ __forceinline__ float finlen(float b, float d) {
    float l = b - d;
    return isfinite(l) ? l : 0.0f;
}

__device__ __forceinline__ void acc_sq(const float4 v, float& s) {
    const float la = finlen(v.x, v.y);
    const float lb = finlen(v.z, v.w);
    s += la * la + lb * lb;
}

__device__ __forceinline__ void acc_sq_max(const float4 v, float& s, float& m) {
    const float la = finlen(v.x, v.y);
    const float lb = finlen(v.z, v.w);
    s += la * la + lb * lb;
    m = fmaxf(m, fmaxf(la, lb));
}

// Block-level reduction of (s0,s1,s2 sums; m0 max). Result valid in thread 0.
__device__ __forceinline__ void block_reduce(float& s0, float& s1, float& s2, float& m0) {
    __shared__ float ls0[NWAVE], ls1[NWAVE], ls2[NWAVE], lm0[NWAVE];
    const int lane = threadIdx.x & 63;
    const int wid  = threadIdx.x >> 6;
    #pragma unroll
    for (int off = 32; off > 0; off >>= 1) {
        s0 += __shfl_down(s0, off);
        s1 += __shfl_down(s1, off);
        s2 += __shfl_down(s2, off);
        m0 = fmaxf(m0, __shfl_down(m0, off));
    }
    if (lane == 0) { ls0[wid] = s0; ls1[wid] = s1; ls2[wid] = s2; lm0[wid] = m0; }
    __syncthreads();
    if (threadIdx.x == 0) {
        #pragma unroll
        for (int w = 1; w < NWAVE; ++w) {
            s0 += ls0[w];
            s1 += ls1[w];
            s2 += ls2[w];
            m0 = fmaxf(m0, lm0[w]);
        }
    }
}

__device__ __forceinline__ void write_final(float* out, float s0, float s1, float s2, float m0) {
    const float top2 = m0 * m0;
    const float t01 = 1.0f - top2;
    const float t0  = s0 - top2;
    out[0] = t01 + t0 + s1 + s2;  // loss
    out[1] = t01;
    out[2] = t0;
    out[3] = s1;
    out[4] = s2;
}

// R1-proven structure: two kernels, three simple sequential grid-stride loops.
// Evidence ledger:
//  - R2/R3: fused finish w/ fence or acq-rel atomics -> L2 wb/inv collapse (100+ us)
//  - R4: fused finish w/ relaxed coherence-point atomics -> still +21 us vs R1
//    (uncached partial reads + same-line RMW contention beat a 4 us dispatch)
//  - R5: 4-way unroll (more loads in flight) -> slight regression; TLP at
//    ~32 waves/CU already hides latency; we sit at the streaming BW ceiling.
// Only change vs R1: float4 partials (dwordx4 store in pass1, coalesced
// float4 loads in pass2).
__global__ __launch_bounds__(BLOCK) void pass1(
    const float* __restrict__ g0, const float* __restrict__ g1,
    const float* __restrict__ g2, float4* __restrict__ part, int npairs)
{
    const float4* a0 = (const float4*)g0;
    const float4* a1 = (const float4*)g1;
    const float4* a2 = (const float4*)g2;
    const long n4 = (long)(npairs >> 1);
    const long tid = (long)blockIdx.x * BLOCK + threadIdx.x;
    const long stride = (long)gridDim.x * BLOCK;

    float s0 = 0.0f, s1 = 0.0f, s2 = 0.0f, m0 = -INFINITY;

    for (long i = tid; i < n4; i += stride) acc_sq_max(a0[i], s0, m0);
    for (long i = tid; i < n4; i += stride) acc_sq(a1[i], s1);
    for (long i = tid; i < n4; i += stride) acc_sq(a2[i], s2);

    // odd-pair scalar tail (not hit for 8M bars, kept for generality)
    if (tid == 0 && (npairs & 1)) {
        const int j = npairs - 1;
        const float l0 = finlen(g0[2 * j], g0[2 * j + 1]);
        const float l1 = finlen(g1[2 * j], g1[2 * j + 1]);
        const float l2 = finlen(g2[2 * j], g2[2 * j + 1]);
        s0 += l0 * l0; s1 += l1 * l1; s2 += l2 * l2;
        m0 = fmaxf(m0, l0);
    }

    block_reduce(s0, s1, s2, m0);

    if (threadIdx.x == 0) {
        part[blockIdx.x] = make_float4(s0, s1, s2, m0);
    }
}

__global__ __launch_bounds__(BLOCK) void pass2(
    const float4* __restrict__ part, int nblocks, float* __restrict__ out)
{
    float s0 = 0.0f, s1 = 0.0f, s2 = 0.0f, m0 = -INFINITY;
    for (int i = threadIdx.x; i < nblocks; i += BLOCK) {
        const float4 p = part[i];
        s0 += p.x;
        s1 += p.y;
        s2 += p.z;
        m0 = fmaxf(m0, p.w);
    }
    block_reduce(s0, s1, s2, m0);
    if (threadIdx.x == 0) write_final(out, s0, s1, s2, m0);
}

extern "C" void kernel_launch(void* const* d_in, const int* in_sizes, int n_in,
                              void* d_out, int out_size, void* d_ws, size_t ws_size,
                              hipStream_t stream) {
    const float* g0 = (const float*)d_in[0];
    const float* g1 = (const float*)d_in[1];
    const float* g2 = (const float*)d_in[2];
    float* out = (float*)d_out;
    float4* part = (float4*)d_ws;

    const int npairs = in_sizes[0] / 2;  // bars per diagram

    int nblocks = NB;  // 256 CUs x 8 blocks co-resident
    const size_t cap = ws_size / sizeof(float4);
    if ((size_t)nblocks > cap) nblocks = (int)cap;
    if (nblocks < 1) nblocks = 1;

    pass1<<<nblocks, BLOCK, 0, stream>>>(g0, g1, g2, part, npairs);
    pass2<<<1, BLOCK, 0, stream>>>(part, nblocks, out);
}